// Round 1
// baseline (9494.593 us; speedup 1.0000x reference)
//
#include <hip/hip_runtime.h>

#define Tn 512
#define In 40
#define Hn 256
#define Kn 4
#define On 16

// Pack W_rec [K*H=1024 rows][H=256 cols] into stream-friendly layout:
// float4 at index (j2*512 + tid) = { W[(k0*H+hp)][2j2], W[(k1*H+hp)][2j2],
//                                    W[(k0*H+hp)][2j2+1], W[(k1*H+hp)][2j2+1] }
// where hp = tid&255, k0 = 2*(tid>>8), k1 = k0+1.
__global__ void pack_wrec(const float* __restrict__ Wr, float* __restrict__ WP) {
    const int j2  = blockIdx.x;            // 0..127
    const int tid = threadIdx.x;           // 0..511
    const int hp  = tid & 255, kh = tid >> 8;
    const int k0 = 2 * kh, k1 = k0 + 1;
    const size_t base = ((size_t)j2 * 512 + tid) * 4;
    WP[base + 0] = Wr[((size_t)(k0 * Hn + hp)) * Hn + 2 * j2];
    WP[base + 1] = Wr[((size_t)(k1 * Hn + hp)) * Hn + 2 * j2];
    WP[base + 2] = Wr[((size_t)(k0 * Hn + hp)) * Hn + 2 * j2 + 1];
    WP[base + 3] = Wr[((size_t)(k1 * Hn + hp)) * Hn + 2 * j2 + 1];
}

// Same packing for W_in [K][H][I=40] over the i dimension (20 pairs).
__global__ void pack_win(const float* __restrict__ Wi, float* __restrict__ WP) {
    const int i2  = blockIdx.x;            // 0..19
    const int tid = threadIdx.x;           // 0..511
    const int hp  = tid & 255, kh = tid >> 8;
    const int k0 = 2 * kh, k1 = k0 + 1;
    const size_t base = ((size_t)i2 * 512 + tid) * 4;
    WP[base + 0] = Wi[((size_t)(k0 * Hn + hp)) * In + 2 * i2];
    WP[base + 1] = Wi[((size_t)(k1 * Hn + hp)) * In + 2 * i2];
    WP[base + 2] = Wi[((size_t)(k0 * Hn + hp)) * In + 2 * i2 + 1];
    WP[base + 3] = Wi[((size_t)(k1 * Hn + hp)) * In + 2 * i2 + 1];
}

// One block = 4 batch rows, 512 threads (8 waves). Thread (hp, kh) owns
// compartments k0=2kh, k1=2kh+1 at hidden index hp, for all 4 rows.
__global__ __launch_bounds__(512) void diru_main(
    const float* __restrict__ x,
    const float* __restrict__ WPr,      // packed rec weights (float4 stream)
    const float* __restrict__ WPi,      // packed input weights
    const float* __restrict__ b_in, const float* __restrict__ b_rec,
    const float* __restrict__ W_gate, const float* __restrict__ b_gate,
    const float* __restrict__ W_fc, const float* __restrict__ b_fc,
    float* __restrict__ out)
{
    const int tid  = threadIdx.x;
    const int hp   = tid & 255;
    const int kh   = tid >> 8;
    const int k0   = 2 * kh, k1 = k0 + 1;
    const int b0   = blockIdx.x * 4;
    const int lane = tid & 63, wav = tid >> 6;

    __shared__ float h_lds[4][Hn];
    __shared__ float x_s[4][In];
    __shared__ float red[8][16];
    __shared__ float hpart[2][4][Hn];

    // Per-thread constants
    float Wg[4][2];
#pragma unroll
    for (int kg = 0; kg < 4; kg++) {
        Wg[kg][0] = W_gate[kg * (Kn * Hn) + k0 * Hn + hp];
        Wg[kg][1] = W_gate[kg * (Kn * Hn) + k1 * Hn + hp];
    }
    const float bb0 = b_in[k0 * Hn + hp] + b_rec[k0 * Hn + hp];
    const float bb1 = b_in[k1 * Hn + hp] + b_rec[k1 * Hn + hp];
    float bg[4];
#pragma unroll
    for (int kg = 0; kg < 4; kg++) bg[kg] = b_gate[kg];

    if (tid < Hn) {
#pragma unroll
        for (int r = 0; r < 4; r++) h_lds[r][tid] = 0.f;
    }

    const float4* __restrict__ WR4 = (const float4*)WPr;
    const float4* __restrict__ WI4 = (const float4*)WPi;

    for (int t = 0; t < Tn; t++) {
        // Stage x_t for the 4 rows
        if (tid < 4 * In) {
            int r = tid / In, i = tid - r * In;
            x_s[r][i] = x[((size_t)(b0 + r) * Tn + t) * In + i];
        }
        __syncthreads();   // x ready; h_lds writes from prev iter visible

        float a0[4], a1[4];
#pragma unroll
        for (int r = 0; r < 4; r++) { a0[r] = bb0; a1[r] = bb1; }

        // Input projection: 20 float4 loads, 16 FMA each
#pragma unroll 4
        for (int i2 = 0; i2 < In / 2; i2++) {
            const float4 w = WI4[i2 * 512 + tid];
#pragma unroll
            for (int r = 0; r < 4; r++) {
                const float xv0 = x_s[r][2 * i2];
                const float xv1 = x_s[r][2 * i2 + 1];
                a0[r] = fmaf(xv0, w.x, a0[r]);
                a1[r] = fmaf(xv0, w.y, a1[r]);
                a0[r] = fmaf(xv1, w.z, a0[r]);
                a1[r] = fmaf(xv1, w.w, a1[r]);
            }
        }

        // Recurrent projection: 128 float4 loads, 16 FMA each
#pragma unroll 4
        for (int j4 = 0; j4 < Hn / 4; j4++) {
            float4 hr[4];
#pragma unroll
            for (int r = 0; r < 4; r++)
                hr[r] = ((const float4*)&h_lds[r][0])[j4];
#pragma unroll
            for (int jj2 = 0; jj2 < 2; jj2++) {
                const float4 w = WR4[(j4 * 2 + jj2) * 512 + tid];
#pragma unroll
                for (int r = 0; r < 4; r++) {
                    const float hv0 = (&hr[r].x)[jj2 * 2];
                    const float hv1 = (&hr[r].x)[jj2 * 2 + 1];
                    a0[r] = fmaf(hv0, w.x, a0[r]);
                    a1[r] = fmaf(hv0, w.y, a1[r]);
                    a0[r] = fmaf(hv1, w.z, a0[r]);
                    a1[r] = fmaf(hv1, w.w, a1[r]);
                }
            }
        }

        // tanh
        float o0[4], o1[4];
#pragma unroll
        for (int r = 0; r < 4; r++) { o0[r] = tanhf(a0[r]); o1[r] = tanhf(a1[r]); }

        // Gate logits: per-thread partial, wave reduce, cross-wave via LDS
        float part[4][4];
#pragma unroll
        for (int r = 0; r < 4; r++)
#pragma unroll
            for (int kg = 0; kg < 4; kg++)
                part[r][kg] = fmaf(o0[r], Wg[kg][0], o1[r] * Wg[kg][1]);

#pragma unroll
        for (int m = 32; m > 0; m >>= 1) {
#pragma unroll
            for (int r = 0; r < 4; r++)
#pragma unroll
                for (int kg = 0; kg < 4; kg++)
                    part[r][kg] += __shfl_xor(part[r][kg], m, 64);
        }
        if (lane == 0) {
#pragma unroll
            for (int r = 0; r < 4; r++)
#pragma unroll
                for (int kg = 0; kg < 4; kg++)
                    red[wav][r * 4 + kg] = part[r][kg];
        }
        __syncthreads();   // red ready; also all h_lds reads of this step done

        // Softmax over the 4 gates (redundant per thread; cheap)
        float wgt[4][4];
#pragma unroll
        for (int r = 0; r < 4; r++) {
            float l[4] = { bg[0], bg[1], bg[2], bg[3] };
#pragma unroll
            for (int w8 = 0; w8 < 8; w8++) {
                const float4 v = *(const float4*)&red[w8][r * 4];
                l[0] += v.x; l[1] += v.y; l[2] += v.z; l[3] += v.w;
            }
            const float mx = fmaxf(fmaxf(l[0], l[1]), fmaxf(l[2], l[3]));
            const float e0 = __expf(l[0] - mx), e1 = __expf(l[1] - mx);
            const float e2 = __expf(l[2] - mx), e3 = __expf(l[3] - mx);
            const float inv = 1.f / (e0 + e1 + e2 + e3);
            wgt[r][0] = e0 * inv; wgt[r][1] = e1 * inv;
            wgt[r][2] = e2 * inv; wgt[r][3] = e3 * inv;
        }

        // h_new: each kh-half contributes its 2 compartments, combine in LDS
#pragma unroll
        for (int r = 0; r < 4; r++)
            hpart[kh][r][hp] = wgt[r][k0] * o0[r] + wgt[r][k1] * o1[r];
        __syncthreads();

        if (tid < Hn) {
#pragma unroll
            for (int r = 0; r < 4; r++)
                h_lds[r][tid] = hpart[0][r][tid] + hpart[1][r][tid];
        }
        // loop-top __syncthreads orders h writes vs next-step reads
    }

    __syncthreads();
    // Final FC: 64 threads, one (row, o) each
    if (tid < 4 * On) {
        const int r = tid >> 4, o = tid & 15;
        float s = b_fc[o];
        for (int j = 0; j < Hn; j++)
            s = fmaf(h_lds[r][j], W_fc[o * Hn + j], s);
        out[(size_t)(b0 + r) * On + o] = s;
    }
}

extern "C" void kernel_launch(void* const* d_in, const int* in_sizes, int n_in,
                              void* d_out, int out_size, void* d_ws, size_t ws_size,
                              hipStream_t stream) {
    const float* x      = (const float*)d_in[0];
    const float* W_in   = (const float*)d_in[1];
    const float* b_in   = (const float*)d_in[2];
    const float* W_rec  = (const float*)d_in[3];
    const float* b_rec  = (const float*)d_in[4];
    const float* W_gate = (const float*)d_in[5];
    const float* b_gate = (const float*)d_in[6];
    const float* W_fc   = (const float*)d_in[7];
    const float* b_fc   = (const float*)d_in[8];
    float* out = (float*)d_out;

    float* ws  = (float*)d_ws;
    float* WPr = ws;                   // 1024*256 = 262144 floats
    float* WPi = ws + 262144;          // 1024*40  =  40960 floats

    pack_wrec<<<128, 512, 0, stream>>>(W_rec, WPr);
    pack_win <<<20,  512, 0, stream>>>(W_in,  WPi);
    diru_main<<<256, 512, 0, stream>>>(x, WPr, WPi, b_in, b_rec,
                                       W_gate, b_gate, W_fc, b_fc, out);
}

// Round 2
// 6465.144 us; speedup vs baseline: 1.4686x; 1.4686x over previous
//
#include <hip/hip_runtime.h>

#define Tn 512
#define In 40
#define Hn 256
#define Kn 4
#define On 16

typedef _Float16 half2v __attribute__((ext_vector_type(2)));

static __device__ __forceinline__ half2v as_h2(unsigned u) {
    union { unsigned u; half2v h; } c; c.u = u; return c.h;
}

static __device__ __forceinline__ float tanh_fast(float x) {
    // 1 - 2/(exp(2x)+1); exp inf -> 1, exp 0 -> -1. ~6 VALU vs ~25 for tanhf.
    float e = __expf(2.f * x);
    return 1.f - 2.f * __builtin_amdgcn_rcpf(e + 1.f);
}

// Pack W_rec [K*H][H] f32 -> fp16 stream: 8 fp16 at ((g*2+c)*512 + tid)*8 are
// W[(k*256+hp)][g*8 .. g*8+7], k = 2*(tid>>8)+c, hp = tid&255.  g=0..31.
__global__ void pack_wrec_h(const float* __restrict__ Wr, _Float16* __restrict__ WP) {
    const int g = blockIdx.x >> 1, c = blockIdx.x & 1;
    const int tid = threadIdx.x;
    const int hp = tid & 255, k = 2 * (tid >> 8) + c;
    const size_t base = ((size_t)(g * 2 + c) * 512 + tid) * 8;
#pragma unroll
    for (int jj = 0; jj < 8; jj++)
        WP[base + jj] = (_Float16)Wr[((size_t)(k * Hn + hp)) * Hn + g * 8 + jj];
}

// Same for W_in [K][H][I=40]: gi=0..4 (8 i each).
__global__ void pack_win_h(const float* __restrict__ Wi, _Float16* __restrict__ WP) {
    const int gi = blockIdx.x >> 1, c = blockIdx.x & 1;
    const int tid = threadIdx.x;
    const int hp = tid & 255, k = 2 * (tid >> 8) + c;
    const size_t base = ((size_t)(gi * 2 + c) * 512 + tid) * 8;
#pragma unroll
    for (int jj = 0; jj < 8; jj++)
        WP[base + jj] = (_Float16)Wi[((size_t)(k * Hn + hp)) * In + gi * 8 + jj];
}

// One block = 4 batch rows, 512 threads (8 waves). Thread (hp, kh) owns
// compartments k0=2kh, k1=2kh+1 at hidden index hp, for all 4 rows.
__global__ __launch_bounds__(512) void diru_main(
    const float* __restrict__ x,
    const _Float16* __restrict__ WPr,
    const _Float16* __restrict__ WPi,
    const float* __restrict__ b_in, const float* __restrict__ b_rec,
    const float* __restrict__ W_gate, const float* __restrict__ b_gate,
    const float* __restrict__ W_fc, const float* __restrict__ b_fc,
    float* __restrict__ out)
{
    const int tid  = threadIdx.x;
    const int hp   = tid & 255;
    const int kh   = tid >> 8;
    const int k0   = 2 * kh, k1 = k0 + 1;
    const int b0   = blockIdx.x * 4;
    const int lane = tid & 63, wav = tid >> 6;

    __shared__ _Float16 hh[4][Hn];       // carried h, fp16 (rows 512B, aligned)
    __shared__ _Float16 x2[4][In];       // x_t, fp16 (rows 80B, 16B-aligned)
    __shared__ float red[8][16];
    __shared__ float hpart[2][4][Hn];

    float Wg[4][2];
#pragma unroll
    for (int kg = 0; kg < 4; kg++) {
        Wg[kg][0] = W_gate[kg * (Kn * Hn) + k0 * Hn + hp];
        Wg[kg][1] = W_gate[kg * (Kn * Hn) + k1 * Hn + hp];
    }
    const float bb0 = b_in[k0 * Hn + hp] + b_rec[k0 * Hn + hp];
    const float bb1 = b_in[k1 * Hn + hp] + b_rec[k1 * Hn + hp];
    float bg[4];
#pragma unroll
    for (int kg = 0; kg < 4; kg++) bg[kg] = b_gate[kg];

    if (tid < Hn) {
#pragma unroll
        for (int r = 0; r < 4; r++) hh[r][tid] = (_Float16)0.f;
    }

    const uint4* __restrict__ WR4 = (const uint4*)WPr;
    const uint4* __restrict__ WI4 = (const uint4*)WPi;

    for (int t = 0; t < Tn; t++) {
        if (tid < 4 * In) {
            const int r = tid / In, i = tid - r * In;
            x2[r][i] = (_Float16)x[((size_t)(b0 + r) * Tn + t) * In + i];
        }
        __syncthreads();   // x ready; hh writes from prev iter visible

        float a0[4], a1[4];
#pragma unroll
        for (int r = 0; r < 4; r++) { a0[r] = bb0; a1[r] = bb1; }

        // Input projection: 10 uint4 weight loads, dot2 over 8-i groups
#pragma unroll
        for (int gi = 0; gi < In / 8; gi++) {
            const uint4 w0 = WI4[(gi * 2 + 0) * 512 + tid];
            const uint4 w1 = WI4[(gi * 2 + 1) * 512 + tid];
#pragma unroll
            for (int r = 0; r < 4; r++) {
                const uint4 xv = ((const uint4*)&x2[r][0])[gi];
                a0[r] = __builtin_amdgcn_fdot2(as_h2(xv.x), as_h2(w0.x), a0[r], false);
                a1[r] = __builtin_amdgcn_fdot2(as_h2(xv.x), as_h2(w1.x), a1[r], false);
                a0[r] = __builtin_amdgcn_fdot2(as_h2(xv.y), as_h2(w0.y), a0[r], false);
                a1[r] = __builtin_amdgcn_fdot2(as_h2(xv.y), as_h2(w1.y), a1[r], false);
                a0[r] = __builtin_amdgcn_fdot2(as_h2(xv.z), as_h2(w0.z), a0[r], false);
                a1[r] = __builtin_amdgcn_fdot2(as_h2(xv.z), as_h2(w1.z), a1[r], false);
                a0[r] = __builtin_amdgcn_fdot2(as_h2(xv.w), as_h2(w0.w), a0[r], false);
                a1[r] = __builtin_amdgcn_fdot2(as_h2(xv.w), as_h2(w1.w), a1[r], false);
            }
        }

        // Recurrent projection: 64 uint4 weight loads, dot2 over 8-j groups
#pragma unroll 4
        for (int g = 0; g < Hn / 8; g++) {
            const uint4 w0 = WR4[(g * 2 + 0) * 512 + tid];
            const uint4 w1 = WR4[(g * 2 + 1) * 512 + tid];
#pragma unroll
            for (int r = 0; r < 4; r++) {
                const uint4 hv = ((const uint4*)&hh[r][0])[g];
                a0[r] = __builtin_amdgcn_fdot2(as_h2(hv.x), as_h2(w0.x), a0[r], false);
                a1[r] = __builtin_amdgcn_fdot2(as_h2(hv.x), as_h2(w1.x), a1[r], false);
                a0[r] = __builtin_amdgcn_fdot2(as_h2(hv.y), as_h2(w0.y), a0[r], false);
                a1[r] = __builtin_amdgcn_fdot2(as_h2(hv.y), as_h2(w1.y), a1[r], false);
                a0[r] = __builtin_amdgcn_fdot2(as_h2(hv.z), as_h2(w0.z), a0[r], false);
                a1[r] = __builtin_amdgcn_fdot2(as_h2(hv.z), as_h2(w1.z), a1[r], false);
                a0[r] = __builtin_amdgcn_fdot2(as_h2(hv.w), as_h2(w0.w), a0[r], false);
                a1[r] = __builtin_amdgcn_fdot2(as_h2(hv.w), as_h2(w1.w), a1[r], false);
            }
        }

        float o0[4], o1[4];
#pragma unroll
        for (int r = 0; r < 4; r++) { o0[r] = tanh_fast(a0[r]); o1[r] = tanh_fast(a1[r]); }

        // Gate logits: per-thread partial, 64-lane shuffle reduce, LDS combine
        float part[4][4];
#pragma unroll
        for (int r = 0; r < 4; r++)
#pragma unroll
            for (int kg = 0; kg < 4; kg++)
                part[r][kg] = fmaf(o0[r], Wg[kg][0], o1[r] * Wg[kg][1]);

#pragma unroll
        for (int m = 32; m > 0; m >>= 1) {
#pragma unroll
            for (int r = 0; r < 4; r++)
#pragma unroll
                for (int kg = 0; kg < 4; kg++)
                    part[r][kg] += __shfl_xor(part[r][kg], m, 64);
        }
        if (lane == 0) {
#pragma unroll
            for (int r = 0; r < 4; r++)
#pragma unroll
                for (int kg = 0; kg < 4; kg++)
                    red[wav][r * 4 + kg] = part[r][kg];
        }
        __syncthreads();   // red ready; all hh reads of this step done

        // Softmax over 4 gates (redundant per thread; cheap)
        float wgt[4][4];
#pragma unroll
        for (int r = 0; r < 4; r++) {
            float l0 = bg[0], l1 = bg[1], l2 = bg[2], l3 = bg[3];
#pragma unroll
            for (int w8 = 0; w8 < 8; w8++) {
                const float4 v = *(const float4*)&red[w8][r * 4];
                l0 += v.x; l1 += v.y; l2 += v.z; l3 += v.w;
            }
            const float mx = fmaxf(fmaxf(l0, l1), fmaxf(l2, l3));
            const float e0 = __expf(l0 - mx), e1 = __expf(l1 - mx);
            const float e2 = __expf(l2 - mx), e3 = __expf(l3 - mx);
            const float inv = __builtin_amdgcn_rcpf(e0 + e1 + e2 + e3);
            wgt[r][0] = e0 * inv; wgt[r][1] = e1 * inv;
            wgt[r][2] = e2 * inv; wgt[r][3] = e3 * inv;
        }

#pragma unroll
        for (int r = 0; r < 4; r++)
            hpart[kh][r][hp] = wgt[r][k0] * o0[r] + wgt[r][k1] * o1[r];
        __syncthreads();

        if (tid < Hn) {
#pragma unroll
            for (int r = 0; r < 4; r++)
                hh[r][tid] = (_Float16)(hpart[0][r][tid] + hpart[1][r][tid]);
        }
        // loop-top __syncthreads orders hh writes vs next-step reads
    }

    __syncthreads();
    if (tid < 4 * On) {
        const int r = tid >> 4, o = tid & 15;
        float s = b_fc[o];
        for (int j = 0; j < Hn; j++)
            s = fmaf((float)hh[r][j], W_fc[o * Hn + j], s);
        out[(size_t)(b0 + r) * On + o] = s;
    }
}

extern "C" void kernel_launch(void* const* d_in, const int* in_sizes, int n_in,
                              void* d_out, int out_size, void* d_ws, size_t ws_size,
                              hipStream_t stream) {
    const float* x      = (const float*)d_in[0];
    const float* W_in   = (const float*)d_in[1];
    const float* b_in   = (const float*)d_in[2];
    const float* W_rec  = (const float*)d_in[3];
    const float* b_rec  = (const float*)d_in[4];
    const float* W_gate = (const float*)d_in[5];
    const float* b_gate = (const float*)d_in[6];
    const float* W_fc   = (const float*)d_in[7];
    const float* b_fc   = (const float*)d_in[8];
    float* out = (float*)d_out;

    _Float16* WPr = (_Float16*)d_ws;          // 1024*256 fp16 = 512 KB
    _Float16* WPi = WPr + 262144;             // 1024*40  fp16 =  80 KB

    pack_wrec_h<<<64, 512, 0, stream>>>(W_rec, WPr);
    pack_win_h <<<10, 512, 0, stream>>>(W_in,  WPi);
    diru_main<<<256, 512, 0, stream>>>(x, WPr, WPi, b_in, b_rec,
                                       W_gate, b_gate, W_fc, b_fc, out);
}